// Round 1
// baseline (1390.888 us; speedup 1.0000x reference)
//
#include <hip/hip_runtime.h>

#define EMBED 1024
#define HEADS 16
#define HDIM  64

// ---------------------------------------------------------------------------
// Kernel 1: fused QKV projection.  C[m][n] = sum_k X[m][k]*W[n][k] + bias[n]
// M = 8*1024 = 8192 rows, K = 1024, three 1024-col weight matrices selected by
// the n-tile index.  Output written directly in [B,H,L,D] layout (head-aligned
// 64-col tiles) into workspace so the attention kernel reads it naturally.
// 64x64 tile, BK=16, 256 threads, 4x4 register tile per thread.
// ---------------------------------------------------------------------------
__global__ __launch_bounds__(256)
void qkv_gemm(const float* __restrict__ X,
              const float* __restrict__ Wq, const float* __restrict__ bq,
              const float* __restrict__ Wk, const float* __restrict__ bk,
              const float* __restrict__ Wv, const float* __restrict__ bv,
              float* __restrict__ Q, float* __restrict__ K, float* __restrict__ V)
{
    __shared__ float As[16][68];   // [k][m], +4 pad: conflict-lite transpose writes
    __shared__ float Bs[16][68];   // [k][n]

    const int t  = threadIdx.x;
    const int nt = blockIdx.x;              // 0..47  (3 matrices x 16 head-tiles)
    const int mt = blockIdx.y;              // 0..127
    const int mat = nt >> 4;                // 0=q 1=k 2=v
    const int c0  = (nt & 15) * 64;         // head-aligned col offset in matrix

    const float* W    = (mat == 0) ? Wq : (mat == 1) ? Wk : Wv;
    const float* bias = (mat == 0) ? bq : (mat == 1) ? bk : bv;
    float*       Out  = (mat == 0) ? Q  : (mat == 1) ? K  : V;

    const int m0   = mt * 64;
    const int lrow = t >> 2;                // 0..63
    const int lk4  = (t & 3) * 4;           // 0,4,8,12
    const float* xa = X + (size_t)(m0 + lrow) * EMBED + lk4;
    const float* wa = W + (size_t)(c0 + lrow) * EMBED + lk4;

    const int tr = t >> 4;                  // 0..15 -> 4 rows each
    const int tc = t & 15;                  // 0..15 -> 4 cols each
    float acc[4][4] = {};

    for (int k0 = 0; k0 < EMBED; k0 += 16) {
        const float4 av  = *(const float4*)(xa + k0);
        const float4 bv4 = *(const float4*)(wa + k0);
        __syncthreads();
        As[lk4+0][lrow] = av.x;  As[lk4+1][lrow] = av.y;
        As[lk4+2][lrow] = av.z;  As[lk4+3][lrow] = av.w;
        Bs[lk4+0][lrow] = bv4.x; Bs[lk4+1][lrow] = bv4.y;
        Bs[lk4+2][lrow] = bv4.z; Bs[lk4+3][lrow] = bv4.w;
        __syncthreads();
#pragma unroll
        for (int kk = 0; kk < 16; ++kk) {
            const float4 a = *(const float4*)&As[kk][tr * 4];
            const float4 b = *(const float4*)&Bs[kk][tc * 4];
            acc[0][0] += a.x * b.x; acc[0][1] += a.x * b.y;
            acc[0][2] += a.x * b.z; acc[0][3] += a.x * b.w;
            acc[1][0] += a.y * b.x; acc[1][1] += a.y * b.y;
            acc[1][2] += a.y * b.z; acc[1][3] += a.y * b.w;
            acc[2][0] += a.z * b.x; acc[2][1] += a.z * b.y;
            acc[2][2] += a.z * b.z; acc[2][3] += a.z * b.w;
            acc[3][0] += a.w * b.x; acc[3][1] += a.w * b.y;
            acc[3][2] += a.w * b.z; acc[3][3] += a.w * b.w;
        }
    }

    // Epilogue: bias add + store to [B,H,L,D]
    const int bidx = m0 >> 10;              // batch (tile never crosses batch)
    const int l0   = m0 & 1023;
    const int h    = c0 >> 6;
    const float b0 = bias[c0 + tc*4 + 0];
    const float b1 = bias[c0 + tc*4 + 1];
    const float b2 = bias[c0 + tc*4 + 2];
    const float b3 = bias[c0 + tc*4 + 3];
#pragma unroll
    for (int i = 0; i < 4; ++i) {
        const size_t row = (size_t)(bidx * HEADS + h) * 1024 + (l0 + tr*4 + i);
        float4 o;
        o.x = acc[i][0] + b0; o.y = acc[i][1] + b1;
        o.z = acc[i][2] + b2; o.w = acc[i][3] + b3;
        *(float4*)(Out + row * HDIM + tc * 4) = o;
    }
}

// ---------------------------------------------------------------------------
// Kernel 2: flash-style attention.  One block = (b, h, 64-query tile).
// Key loop over 16 tiles of 64 keys.  S = Q*K^T as a register-tiled LDS GEMM
// (4 queries x 4 keys per thread), online softmax with shfl-xor reductions
// across the 16 key-column lanes, P staged transposed through LDS into the
// P*V GEMM (4 queries x 4 dims per thread).  LDS = 4 x 16KB = 64KB.
// ---------------------------------------------------------------------------
__global__ __launch_bounds__(256)
void attn(const float* __restrict__ Q, const float* __restrict__ K,
          const float* __restrict__ V, float* __restrict__ out)
{
    __shared__ float QsT[64][64];   // [d][q], pre-scaled by 1/8
    __shared__ float KsT[64][64];   // [d][k]
    __shared__ float Vs [64][64];   // [k][d]
    __shared__ float PsT[64][64];   // [k][q]

    const int t  = threadIdx.x;
    const int qt = blockIdx.x, h = blockIdx.y, b = blockIdx.z;
    const size_t base = (size_t)(b * HEADS + h) * 1024 * HDIM;

    const int tr = t >> 4;          // 0..15 -> 4 query rows
    const int tc = t & 15;          // 0..15 -> 4 key cols / 4 dims

    // Load + transpose + scale Q tile
#pragma unroll
    for (int rep = 0; rep < 4; ++rep) {
        const int idx = t + rep * 256;
        const int row = idx >> 4;            // query 0..63
        const int c4  = (idx & 15) * 4;      // d offset
        const float4 v = *(const float4*)(Q + base + (size_t)(qt*64 + row)*HDIM + c4);
        QsT[c4+0][row] = v.x * 0.125f;
        QsT[c4+1][row] = v.y * 0.125f;
        QsT[c4+2][row] = v.z * 0.125f;
        QsT[c4+3][row] = v.w * 0.125f;
    }

    float O[4][4] = {};
    float m_i[4] = {-1e30f, -1e30f, -1e30f, -1e30f};
    float l_i[4] = {0.f, 0.f, 0.f, 0.f};

    for (int kt = 0; kt < 16; ++kt) {
        __syncthreads();   // prev iter's reads of KsT/Vs/PsT done
#pragma unroll
        for (int rep = 0; rep < 4; ++rep) {
            const int idx = t + rep * 256;
            const int row = idx >> 4;
            const int c4  = (idx & 15) * 4;
            const float4 kv = *(const float4*)(K + base + (size_t)(kt*64 + row)*HDIM + c4);
            KsT[c4+0][row] = kv.x; KsT[c4+1][row] = kv.y;
            KsT[c4+2][row] = kv.z; KsT[c4+3][row] = kv.w;
            const float4 vv = *(const float4*)(V + base + (size_t)(kt*64 + row)*HDIM + c4);
            *(float4*)&Vs[row][c4] = vv;
        }
        __syncthreads();

        // S tile: 4x4 scores per thread
        float s[4][4] = {};
#pragma unroll 8
        for (int d = 0; d < 64; ++d) {
            const float4 a = *(const float4*)&QsT[d][tr * 4];
            const float4 k4 = *(const float4*)&KsT[d][tc * 4];
            s[0][0] += a.x * k4.x; s[0][1] += a.x * k4.y;
            s[0][2] += a.x * k4.z; s[0][3] += a.x * k4.w;
            s[1][0] += a.y * k4.x; s[1][1] += a.y * k4.y;
            s[1][2] += a.y * k4.z; s[1][3] += a.y * k4.w;
            s[2][0] += a.z * k4.x; s[2][1] += a.z * k4.y;
            s[2][2] += a.z * k4.z; s[2][3] += a.z * k4.w;
            s[3][0] += a.w * k4.x; s[3][1] += a.w * k4.y;
            s[3][2] += a.w * k4.z; s[3][3] += a.w * k4.w;
        }

        // Online softmax per query row (state replicated across the 16 tc lanes)
        float p[4][4];
#pragma unroll
        for (int i = 0; i < 4; ++i) {
            float rm = fmaxf(fmaxf(s[i][0], s[i][1]), fmaxf(s[i][2], s[i][3]));
            rm = fmaxf(rm, __shfl_xor(rm, 1));
            rm = fmaxf(rm, __shfl_xor(rm, 2));
            rm = fmaxf(rm, __shfl_xor(rm, 4));
            rm = fmaxf(rm, __shfl_xor(rm, 8));
            const float mnew  = fmaxf(m_i[i], rm);
            const float alpha = __expf(m_i[i] - mnew);
            m_i[i] = mnew;
            float rs = 0.f;
#pragma unroll
            for (int j = 0; j < 4; ++j) { p[i][j] = __expf(s[i][j] - mnew); rs += p[i][j]; }
            rs += __shfl_xor(rs, 1);
            rs += __shfl_xor(rs, 2);
            rs += __shfl_xor(rs, 4);
            rs += __shfl_xor(rs, 8);
            l_i[i] = l_i[i] * alpha + rs;
            O[i][0] *= alpha; O[i][1] *= alpha; O[i][2] *= alpha; O[i][3] *= alpha;
        }

        // Stage P transposed: PsT[key][query]
#pragma unroll
        for (int j = 0; j < 4; ++j) {
            float4 pv;
            pv.x = p[0][j]; pv.y = p[1][j]; pv.z = p[2][j]; pv.w = p[3][j];
            *(float4*)&PsT[tc*4 + j][tr*4] = pv;
        }
        __syncthreads();

        // O += P * V : 4 queries x 4 dims per thread
#pragma unroll 8
        for (int k = 0; k < 64; ++k) {
            const float4 pa = *(const float4*)&PsT[k][tr * 4];
            const float4 vv = *(const float4*)&Vs [k][tc * 4];
            O[0][0] += pa.x * vv.x; O[0][1] += pa.x * vv.y;
            O[0][2] += pa.x * vv.z; O[0][3] += pa.x * vv.w;
            O[1][0] += pa.y * vv.x; O[1][1] += pa.y * vv.y;
            O[1][2] += pa.y * vv.z; O[1][3] += pa.y * vv.w;
            O[2][0] += pa.z * vv.x; O[2][1] += pa.z * vv.y;
            O[2][2] += pa.z * vv.z; O[2][3] += pa.z * vv.w;
            O[3][0] += pa.w * vv.x; O[3][1] += pa.w * vv.y;
            O[3][2] += pa.w * vv.z; O[3][3] += pa.w * vv.w;
        }
    }

    // Normalize + store (flat [b,h,l,d] order == reference's no-transpose reshape)
#pragma unroll
    for (int i = 0; i < 4; ++i) {
        const float inv = 1.0f / l_i[i];
        float4 o;
        o.x = O[i][0] * inv; o.y = O[i][1] * inv;
        o.z = O[i][2] * inv; o.w = O[i][3] * inv;
        *(float4*)(out + base + (size_t)(qt*64 + tr*4 + i)*HDIM + tc*4) = o;
    }
}

extern "C" void kernel_launch(void* const* d_in, const int* in_sizes, int n_in,
                              void* d_out, int out_size, void* d_ws, size_t ws_size,
                              hipStream_t stream)
{
    const float* X  = (const float*)d_in[0];
    const float* Wq = (const float*)d_in[1];
    const float* bq = (const float*)d_in[2];
    const float* Wk = (const float*)d_in[3];
    const float* bk = (const float*)d_in[4];
    const float* Wv = (const float*)d_in[5];
    const float* bv = (const float*)d_in[6];
    float* out = (float*)d_out;

    const size_t per = (size_t)8 * HEADS * 1024 * HDIM;  // 8.4M floats each
    float* Q = (float*)d_ws;
    float* K = Q + per;
    float* V = K + per;

    qkv_gemm<<<dim3(48, 128), 256, 0, stream>>>(X, Wq, bq, Wk, bk, Wv, bv, Q, K, V);
    attn<<<dim3(16, HEADS, 8), 256, 0, stream>>>(Q, K, V, out);
}

// Round 2
// 895.343 us; speedup vs baseline: 1.5535x; 1.5535x over previous
//
#include <hip/hip_runtime.h>

#define EMBED 1024
#define HEADS 16
#define HDIM  64

typedef __attribute__((ext_vector_type(8))) short bf16x8;
typedef __attribute__((ext_vector_type(4))) float f32x4;

// ---------------------------------------------------------------------------
// Kernel 0: split fp32 -> bf16 hi + bf16 lo (RNE).  x = hi + lo exactly to
// ~2^-18 relative; 3-pass MFMA on (hi,lo) reproduces fp32 accuracy.
// ---------------------------------------------------------------------------
__device__ __forceinline__ unsigned bf16_rne(float f) {
    unsigned u = __float_as_uint(f);
    return (u + 0x7FFFu + ((u >> 16) & 1u)) >> 16;
}

__global__ __launch_bounds__(256)
void split_bf16(const float* __restrict__ in, short* __restrict__ hi,
                short* __restrict__ lo, int n)
{
    int i = (blockIdx.x * 256 + threadIdx.x) * 8;
    if (i >= n) return;
    float4 a = *(const float4*)(in + i);
    float4 b = *(const float4*)(in + i + 4);
    float f[8] = {a.x, a.y, a.z, a.w, b.x, b.y, b.z, b.w};
    union { unsigned short us[8]; uint4 v; } H, L;
#pragma unroll
    for (int e = 0; e < 8; ++e) {
        unsigned hb = bf16_rne(f[e]);
        H.us[e] = (unsigned short)hb;
        float r = f[e] - __uint_as_float(hb << 16);
        L.us[e] = (unsigned short)bf16_rne(r);
    }
    *(uint4*)(hi + i) = H.v;
    *(uint4*)(lo + i) = L.v;
}

// ---------------------------------------------------------------------------
// Kernel 1: QKV projection, bf16-split MFMA.  C[m][n] = sum_k X[m][k]*W[n][k]
// + bias[n], M=8192, K=1024, W = 3 concatenated 1024x1024 matrices (rows are
// output cols, i.e. B^T — matches MFMA B-frag as rows over k).
// 128x128 tile, BK=32, 256 thr = 4 waves (2x2), wave tile 64x64 = 4x4 MFMAs
// of 16x16x32.  3 MFMA per position: ah*bh + ah*bl + al*bh (fp32-accurate).
// LDS k-slab layout [slab][row][8] so global_load_lds (wave-uniform base +
// lane*16) and conflict-free ds_read_b128 frag loads both work.
// Output written directly to Q/K/V in [B,H,L,D] fp32.
// ---------------------------------------------------------------------------
#define AS1 __attribute__((address_space(1)))
#define AS3 __attribute__((address_space(3)))

__global__ __launch_bounds__(256)
void qkv_mfma(const short* __restrict__ Xh, const short* __restrict__ Xl,
              const short* __restrict__ Wh, const short* __restrict__ Wl,
              const float* __restrict__ bq, const float* __restrict__ bk,
              const float* __restrict__ bv,
              float* __restrict__ Q, float* __restrict__ K, float* __restrict__ V)
{
    __shared__ short Ah[4096], Al[4096], Bh[4096], Bl[4096];  // 4 slabs x 128 rows x 8

    const int t  = threadIdx.x;
    const int nt = blockIdx.x;          // 0..23
    const int mt = blockIdx.y;          // 0..63
    const int m0 = mt * 128, n0 = nt * 128;

    const int lane = t & 63, quad = lane >> 4, l16 = lane & 15;
    const int w = t >> 6, wm = w >> 1, wn = w & 1;

    // staging: thread handles chunks c0 = t (slabs 0/1) and c0+256 (slabs 2/3)
    const int r0 = t & 127, s0 = t >> 7;
    const short* gA_h = Xh + (size_t)(m0 + r0) * EMBED + s0 * 8;
    const short* gA_l = Xl + (size_t)(m0 + r0) * EMBED + s0 * 8;
    const short* gB_h = Wh + (size_t)(n0 + r0) * EMBED + s0 * 8;
    const short* gB_l = Wl + (size_t)(n0 + r0) * EMBED + s0 * 8;

    f32x4 acc[4][4];
#pragma unroll
    for (int i = 0; i < 4; ++i)
#pragma unroll
        for (int j = 0; j < 4; ++j) acc[i][j] = (f32x4){0.f, 0.f, 0.f, 0.f};

    for (int k0 = 0; k0 < EMBED; k0 += 32) {
        __syncthreads();
        __builtin_amdgcn_global_load_lds((const AS1 void*)(gA_h + k0),      (AS3 void*)&Ah[t * 8],         16, 0, 0);
        __builtin_amdgcn_global_load_lds((const AS1 void*)(gA_h + k0 + 16), (AS3 void*)&Ah[(t + 256) * 8], 16, 0, 0);
        __builtin_amdgcn_global_load_lds((const AS1 void*)(gA_l + k0),      (AS3 void*)&Al[t * 8],         16, 0, 0);
        __builtin_amdgcn_global_load_lds((const AS1 void*)(gA_l + k0 + 16), (AS3 void*)&Al[(t + 256) * 8], 16, 0, 0);
        __builtin_amdgcn_global_load_lds((const AS1 void*)(gB_h + k0),      (AS3 void*)&Bh[t * 8],         16, 0, 0);
        __builtin_amdgcn_global_load_lds((const AS1 void*)(gB_h + k0 + 16), (AS3 void*)&Bh[(t + 256) * 8], 16, 0, 0);
        __builtin_amdgcn_global_load_lds((const AS1 void*)(gB_l + k0),      (AS3 void*)&Bl[t * 8],         16, 0, 0);
        __builtin_amdgcn_global_load_lds((const AS1 void*)(gB_l + k0 + 16), (AS3 void*)&Bl[(t + 256) * 8], 16, 0, 0);
        __syncthreads();

        bf16x8 ah[4], al[4], bh[4], bl[4];
#pragma unroll
        for (int mi = 0; mi < 4; ++mi) {
            const int c = quad * 128 + wm * 64 + mi * 16 + l16;
            ah[mi] = *(const bf16x8*)&Ah[c * 8];
            al[mi] = *(const bf16x8*)&Al[c * 8];
        }
#pragma unroll
        for (int ni = 0; ni < 4; ++ni) {
            const int c = quad * 128 + wn * 64 + ni * 16 + l16;
            bh[ni] = *(const bf16x8*)&Bh[c * 8];
            bl[ni] = *(const bf16x8*)&Bl[c * 8];
        }
#pragma unroll
        for (int mi = 0; mi < 4; ++mi)
#pragma unroll
            for (int ni = 0; ni < 4; ++ni) {
                acc[mi][ni] = __builtin_amdgcn_mfma_f32_16x16x32_bf16(ah[mi], bh[ni], acc[mi][ni], 0, 0, 0);
                acc[mi][ni] = __builtin_amdgcn_mfma_f32_16x16x32_bf16(ah[mi], bl[ni], acc[mi][ni], 0, 0, 0);
                acc[mi][ni] = __builtin_amdgcn_mfma_f32_16x16x32_bf16(al[mi], bh[ni], acc[mi][ni], 0, 0, 0);
            }
    }

    // Epilogue: bias + store to [B,H,L,D].  C/D: col(n)=lane&15, row(m)=quad*4+reg.
    const int mat = n0 >> 10;
    float* Out = (mat == 0) ? Q : (mat == 1) ? K : V;
    const float* bias = (mat == 0) ? bq : (mat == 1) ? bk : bv;
    const int nm_base = (n0 & 1023) + wn * 64;
    const int b = m0 >> 10;
    const int l_base = (m0 & 1023) + wm * 64 + quad * 4;
    float bias_v[4];
#pragma unroll
    for (int ni = 0; ni < 4; ++ni) bias_v[ni] = bias[nm_base + ni * 16 + l16];

#pragma unroll
    for (int mi = 0; mi < 4; ++mi) {
#pragma unroll
        for (int ni = 0; ni < 4; ++ni) {
            const int nm = nm_base + ni * 16 + l16;
            const int head = nm >> 6, d = nm & 63;
            const int l0 = l_base + mi * 16;
            float* p = Out + (((size_t)(b * HEADS + head) * 1024 + l0) * HDIM + d);
#pragma unroll
            for (int r = 0; r < 4; ++r) p[(size_t)r * HDIM] = acc[mi][ni][r] + bias_v[ni];
        }
    }
}

// ---------------------------------------------------------------------------
// Kernel 2: flash-style fp32 attention (unchanged from R1).
// ---------------------------------------------------------------------------
__global__ __launch_bounds__(256)
void attn(const float* __restrict__ Q, const float* __restrict__ K,
          const float* __restrict__ V, float* __restrict__ out)
{
    __shared__ float QsT[64][64];
    __shared__ float KsT[64][64];
    __shared__ float Vs [64][64];
    __shared__ float PsT[64][64];

    const int t  = threadIdx.x;
    const int qt = blockIdx.x, h = blockIdx.y, b = blockIdx.z;
    const size_t base = (size_t)(b * HEADS + h) * 1024 * HDIM;

    const int tr = t >> 4;
    const int tc = t & 15;

#pragma unroll
    for (int rep = 0; rep < 4; ++rep) {
        const int idx = t + rep * 256;
        const int row = idx >> 4;
        const int c4  = (idx & 15) * 4;
        const float4 v = *(const float4*)(Q + base + (size_t)(qt*64 + row)*HDIM + c4);
        QsT[c4+0][row] = v.x * 0.125f;
        QsT[c4+1][row] = v.y * 0.125f;
        QsT[c4+2][row] = v.z * 0.125f;
        QsT[c4+3][row] = v.w * 0.125f;
    }

    float O[4][4] = {};
    float m_i[4] = {-1e30f, -1e30f, -1e30f, -1e30f};
    float l_i[4] = {0.f, 0.f, 0.f, 0.f};

    for (int kt = 0; kt < 16; ++kt) {
        __syncthreads();
#pragma unroll
        for (int rep = 0; rep < 4; ++rep) {
            const int idx = t + rep * 256;
            const int row = idx >> 4;
            const int c4  = (idx & 15) * 4;
            const float4 kv = *(const float4*)(K + base + (size_t)(kt*64 + row)*HDIM + c4);
            KsT[c4+0][row] = kv.x; KsT[c4+1][row] = kv.y;
            KsT[c4+2][row] = kv.z; KsT[c4+3][row] = kv.w;
            const float4 vv = *(const float4*)(V + base + (size_t)(kt*64 + row)*HDIM + c4);
            *(float4*)&Vs[row][c4] = vv;
        }
        __syncthreads();

        float s[4][4] = {};
#pragma unroll 8
        for (int d = 0; d < 64; ++d) {
            const float4 a = *(const float4*)&QsT[d][tr * 4];
            const float4 k4 = *(const float4*)&KsT[d][tc * 4];
            s[0][0] += a.x * k4.x; s[0][1] += a.x * k4.y;
            s[0][2] += a.x * k4.z; s[0][3] += a.x * k4.w;
            s[1][0] += a.y * k4.x; s[1][1] += a.y * k4.y;
            s[1][2] += a.y * k4.z; s[1][3] += a.y * k4.w;
            s[2][0] += a.z * k4.x; s[2][1] += a.z * k4.y;
            s[2][2] += a.z * k4.z; s[2][3] += a.z * k4.w;
            s[3][0] += a.w * k4.x; s[3][1] += a.w * k4.y;
            s[3][2] += a.w * k4.z; s[3][3] += a.w * k4.w;
        }

        float p[4][4];
#pragma unroll
        for (int i = 0; i < 4; ++i) {
            float rm = fmaxf(fmaxf(s[i][0], s[i][1]), fmaxf(s[i][2], s[i][3]));
            rm = fmaxf(rm, __shfl_xor(rm, 1));
            rm = fmaxf(rm, __shfl_xor(rm, 2));
            rm = fmaxf(rm, __shfl_xor(rm, 4));
            rm = fmaxf(rm, __shfl_xor(rm, 8));
            const float mnew  = fmaxf(m_i[i], rm);
            const float alpha = __expf(m_i[i] - mnew);
            m_i[i] = mnew;
            float rs = 0.f;
#pragma unroll
            for (int j = 0; j < 4; ++j) { p[i][j] = __expf(s[i][j] - mnew); rs += p[i][j]; }
            rs += __shfl_xor(rs, 1);
            rs += __shfl_xor(rs, 2);
            rs += __shfl_xor(rs, 4);
            rs += __shfl_xor(rs, 8);
            l_i[i] = l_i[i] * alpha + rs;
            O[i][0] *= alpha; O[i][1] *= alpha; O[i][2] *= alpha; O[i][3] *= alpha;
        }

#pragma unroll
        for (int j = 0; j < 4; ++j) {
            float4 pv;
            pv.x = p[0][j]; pv.y = p[1][j]; pv.z = p[2][j]; pv.w = p[3][j];
            *(float4*)&PsT[tc*4 + j][tr*4] = pv;
        }
        __syncthreads();

#pragma unroll 8
        for (int k = 0; k < 64; ++k) {
            const float4 pa = *(const float4*)&PsT[k][tr * 4];
            const float4 vv = *(const float4*)&Vs [k][tc * 4];
            O[0][0] += pa.x * vv.x; O[0][1] += pa.x * vv.y;
            O[0][2] += pa.x * vv.z; O[0][3] += pa.x * vv.w;
            O[1][0] += pa.y * vv.x; O[1][1] += pa.y * vv.y;
            O[1][2] += pa.y * vv.z; O[1][3] += pa.y * vv.w;
            O[2][0] += pa.z * vv.x; O[2][1] += pa.z * vv.y;
            O[2][2] += pa.z * vv.z; O[2][3] += pa.z * vv.w;
            O[3][0] += pa.w * vv.x; O[3][1] += pa.w * vv.y;
            O[3][2] += pa.w * vv.z; O[3][3] += pa.w * vv.w;
        }
    }

#pragma unroll
    for (int i = 0; i < 4; ++i) {
        const float inv = 1.0f / l_i[i];
        float4 o;
        o.x = O[i][0] * inv; o.y = O[i][1] * inv;
        o.z = O[i][2] * inv; o.w = O[i][3] * inv;
        *(float4*)(out + base + (size_t)(qt*64 + tr*4 + i)*HDIM + tc*4) = o;
    }
}

extern "C" void kernel_launch(void* const* d_in, const int* in_sizes, int n_in,
                              void* d_out, int out_size, void* d_ws, size_t ws_size,
                              hipStream_t stream)
{
    const float* X  = (const float*)d_in[0];
    const float* Wq = (const float*)d_in[1];
    const float* bq = (const float*)d_in[2];
    const float* Wk = (const float*)d_in[3];
    const float* bk = (const float*)d_in[4];
    const float* Wv = (const float*)d_in[5];
    const float* bv = (const float*)d_in[6];
    float* out = (float*)d_out;

    const size_t per = (size_t)8 * HEADS * 1024 * HDIM;   // 8,388,608 floats
    float* Q = (float*)d_ws;
    float* K = Q + per;
    float* V = K + per;
    short* sb = (short*)(V + per);
    short* Xh = sb;                       // 8,388,608 shorts
    short* Xl = Xh + per;
    short* Wh = Xl + per;                 // 3 x 1,048,576
    short* Wl = Wh + 3 * 1048576;

    const int nX = (int)per;              // 8192*1024
    const int nW = 1048576;               // 1024*1024

    split_bf16<<<nX / (8 * 256), 256, 0, stream>>>(X,  Xh, Xl, nX);
    split_bf16<<<nW / (8 * 256), 256, 0, stream>>>(Wq, Wh,               Wl,               nW);
    split_bf16<<<nW / (8 * 256), 256, 0, stream>>>(Wk, Wh + nW,          Wl + nW,          nW);
    split_bf16<<<nW / (8 * 256), 256, 0, stream>>>(Wv, Wh + 2 * nW,      Wl + 2 * nW,      nW);

    qkv_mfma<<<dim3(24, 64), 256, 0, stream>>>(Xh, Xl, Wh, Wl, bq, bk, bv, Q, K, V);
    attn<<<dim3(16, HEADS, 8), 256, 0, stream>>>(Q, K, V, out);
}

// Round 3
// 438.035 us; speedup vs baseline: 3.1753x; 2.0440x over previous
//
#include <hip/hip_runtime.h>

#define EMBED 1024
#define HEADS 16
#define HDIM  64

typedef __attribute__((ext_vector_type(8))) short bf16x8;
typedef __attribute__((ext_vector_type(4))) float f32x4;

#define AS1 __attribute__((address_space(1)))
#define AS3 __attribute__((address_space(3)))

// ---------------------------------------------------------------------------
// fp32 -> bf16 RNE
// ---------------------------------------------------------------------------
__device__ __forceinline__ unsigned bf16_rne(float f) {
    unsigned u = __float_as_uint(f);
    return (u + 0x7FFFu + ((u >> 16) & 1u)) >> 16;
}

// ---------------------------------------------------------------------------
// Kernel 0: split fp32 -> bf16 hi + bf16 lo (x = hi + lo to ~2^-17 rel).
// ---------------------------------------------------------------------------
__global__ __launch_bounds__(256)
void split_bf16(const float* __restrict__ in, short* __restrict__ hi,
                short* __restrict__ lo, int n)
{
    int i = (blockIdx.x * 256 + threadIdx.x) * 8;
    if (i >= n) return;
    float4 a = *(const float4*)(in + i);
    float4 b = *(const float4*)(in + i + 4);
    float f[8] = {a.x, a.y, a.z, a.w, b.x, b.y, b.z, b.w};
    union { unsigned short us[8]; uint4 v; } H, L;
#pragma unroll
    for (int e = 0; e < 8; ++e) {
        unsigned hb = bf16_rne(f[e]);
        H.us[e] = (unsigned short)hb;
        float r = f[e] - __uint_as_float(hb << 16);
        L.us[e] = (unsigned short)bf16_rne(r);
    }
    *(uint4*)(hi + i) = H.v;
    *(uint4*)(lo + i) = L.v;
}

// ---------------------------------------------------------------------------
// Kernel 1: QKV projection, bf16-split MFMA (fp32-accurate via 3 passes).
// Emits bf16: Q (pre-scaled 1/8) and K in [b,h,l,d]; V transposed [b,h,d,l]
// so the attention kernel can stage every tile with global_load_lds.
// ---------------------------------------------------------------------------
__global__ __launch_bounds__(256)
void qkv_mfma(const short* __restrict__ Xh, const short* __restrict__ Xl,
              const short* __restrict__ Wh, const short* __restrict__ Wl,
              const float* __restrict__ bq, const float* __restrict__ bk,
              const float* __restrict__ bv,
              short* __restrict__ Qb, short* __restrict__ Kb, short* __restrict__ Vt)
{
    __shared__ short Ah[4096], Al[4096], Bh[4096], Bl[4096];  // [chunk][row128][8]

    const int t  = threadIdx.x;
    const int nt = blockIdx.x;          // 0..23
    const int mt = blockIdx.y;          // 0..63
    const int m0 = mt * 128, n0 = nt * 128;

    const int lane = t & 63, quad = lane >> 4, l16 = lane & 15;
    const int w = t >> 6, wm = w >> 1, wn = w & 1;

    const int r0 = t & 127, s0 = t >> 7;
    const short* gA_h = Xh + (size_t)(m0 + r0) * EMBED + s0 * 8;
    const short* gA_l = Xl + (size_t)(m0 + r0) * EMBED + s0 * 8;
    const short* gB_h = Wh + (size_t)(n0 + r0) * EMBED + s0 * 8;
    const short* gB_l = Wl + (size_t)(n0 + r0) * EMBED + s0 * 8;

    f32x4 acc[4][4];
#pragma unroll
    for (int i = 0; i < 4; ++i)
#pragma unroll
        for (int j = 0; j < 4; ++j) acc[i][j] = (f32x4){0.f, 0.f, 0.f, 0.f};

    for (int k0 = 0; k0 < EMBED; k0 += 32) {
        __syncthreads();
        __builtin_amdgcn_global_load_lds((const AS1 void*)(gA_h + k0),      (AS3 void*)&Ah[t * 8],         16, 0, 0);
        __builtin_amdgcn_global_load_lds((const AS1 void*)(gA_h + k0 + 16), (AS3 void*)&Ah[(t + 256) * 8], 16, 0, 0);
        __builtin_amdgcn_global_load_lds((const AS1 void*)(gA_l + k0),      (AS3 void*)&Al[t * 8],         16, 0, 0);
        __builtin_amdgcn_global_load_lds((const AS1 void*)(gA_l + k0 + 16), (AS3 void*)&Al[(t + 256) * 8], 16, 0, 0);
        __builtin_amdgcn_global_load_lds((const AS1 void*)(gB_h + k0),      (AS3 void*)&Bh[t * 8],         16, 0, 0);
        __builtin_amdgcn_global_load_lds((const AS1 void*)(gB_h + k0 + 16), (AS3 void*)&Bh[(t + 256) * 8], 16, 0, 0);
        __builtin_amdgcn_global_load_lds((const AS1 void*)(gB_l + k0),      (AS3 void*)&Bl[t * 8],         16, 0, 0);
        __builtin_amdgcn_global_load_lds((const AS1 void*)(gB_l + k0 + 16), (AS3 void*)&Bl[(t + 256) * 8], 16, 0, 0);
        __syncthreads();

        bf16x8 ah[4], al[4], bh[4], bl[4];
#pragma unroll
        for (int mi = 0; mi < 4; ++mi) {
            const int c = quad * 128 + wm * 64 + mi * 16 + l16;
            ah[mi] = *(const bf16x8*)&Ah[c * 8];
            al[mi] = *(const bf16x8*)&Al[c * 8];
        }
#pragma unroll
        for (int ni = 0; ni < 4; ++ni) {
            const int c = quad * 128 + wn * 64 + ni * 16 + l16;
            bh[ni] = *(const bf16x8*)&Bh[c * 8];
            bl[ni] = *(const bf16x8*)&Bl[c * 8];
        }
#pragma unroll
        for (int mi = 0; mi < 4; ++mi)
#pragma unroll
            for (int ni = 0; ni < 4; ++ni) {
                acc[mi][ni] = __builtin_amdgcn_mfma_f32_16x16x32_bf16(ah[mi], bh[ni], acc[mi][ni], 0, 0, 0);
                acc[mi][ni] = __builtin_amdgcn_mfma_f32_16x16x32_bf16(ah[mi], bl[ni], acc[mi][ni], 0, 0, 0);
                acc[mi][ni] = __builtin_amdgcn_mfma_f32_16x16x32_bf16(al[mi], bh[ni], acc[mi][ni], 0, 0, 0);
            }
    }

    // Epilogue: bias (+1/8 scale for Q), cast bf16, store.
    const int mat = n0 >> 10;                 // 0=q 1=k 2=v
    const float* bias = (mat == 0) ? bq : (mat == 1) ? bk : bv;
    const float scale = (mat == 0) ? 0.125f : 1.0f;
    const int b = m0 >> 10;
    const int nm_base = (n0 & 1023) + wn * 64;
    const int l_base  = (m0 & 1023) + wm * 64 + quad * 4;
    float bias_v[4];
#pragma unroll
    for (int ni = 0; ni < 4; ++ni) bias_v[ni] = bias[nm_base + ni * 16 + l16];

#pragma unroll
    for (int mi = 0; mi < 4; ++mi) {
#pragma unroll
        for (int ni = 0; ni < 4; ++ni) {
            const int nm = nm_base + ni * 16 + l16;
            const int head = nm >> 6, d = nm & 63;
            const int bh_i = b * HEADS + head;
            const int l0 = l_base + mi * 16;
#pragma unroll
            for (int r = 0; r < 4; ++r) {
                const float v = (acc[mi][ni][r] + bias_v[ni]) * scale;
                const unsigned short u = (unsigned short)bf16_rne(v);
                if (mat == 2)
                    Vt[(size_t)(bh_i * 64 + d) * 1024 + (l0 + r)] = (short)u;
                else {
                    short* O = (mat == 0) ? Qb : Kb;
                    O[((size_t)bh_i * 1024 + (l0 + r)) * 64 + d] = (short)u;
                }
            }
        }
    }
}

// ---------------------------------------------------------------------------
// Kernel 2: MFMA flash attention.  Block = (qt 64 queries, h, b), 4 waves,
// wave owns 16 queries.  Tiles staged via global_load_lds into [chunk][row][8]
// bf16 layout; S and PV via 16x16x32 bf16 MFMA; online softmax in fp32 on
// C-frags; P round-trips through wave-private LDS into A-layout.
// ---------------------------------------------------------------------------
__global__ __launch_bounds__(256)
void attn_mfma(const short* __restrict__ Qb, const short* __restrict__ Kb,
               const short* __restrict__ Vt, float* __restrict__ out)
{
    __shared__ short Qs[4096];   // [chunk8][qrow64][8]
    __shared__ short Ks[4096];   // [chunk8][krow64][8]
    __shared__ short Vs[4096];   // [kchunk8][dimrow64][8]   (from V^T global)
    __shared__ short Ps[4096];   // per-wave 1024: [kchunk8][qrow16][8]

    const int t  = threadIdx.x;
    const int qt = blockIdx.x, h = blockIdx.y, b = blockIdx.z;
    const int bh = b * HEADS + h;
    const int lane = t & 63, quad = lane >> 4, l16 = lane & 15;
    const int w = t >> 6;
    short* Psw = &Ps[w * 1024];

    const int srow = t & 63, schunk = t >> 6;   // staging: row, chunk (0..3 / +4)

    // Stage Q tile once (64 rows x 64 dims bf16, scaled 1/8 already)
    {
        const short* g = Qb + ((size_t)bh * 1024 + qt * 64 + srow) * 64 + schunk * 8;
        __builtin_amdgcn_global_load_lds((const AS1 void*)g,        (AS3 void*)&Qs[t * 8],         16, 0, 0);
        __builtin_amdgcn_global_load_lds((const AS1 void*)(g + 32), (AS3 void*)&Qs[(t + 256) * 8], 16, 0, 0);
    }

    f32x4 O[4];
#pragma unroll
    for (int i = 0; i < 4; ++i) O[i] = (f32x4){0.f, 0.f, 0.f, 0.f};
    float m_i[4] = {-1e30f, -1e30f, -1e30f, -1e30f};
    float l_i[4] = {0.f, 0.f, 0.f, 0.f};

    for (int kt = 0; kt < 16; ++kt) {
        __syncthreads();   // previous iter's Ks/Vs reads complete
        {
            const short* gk = Kb + ((size_t)bh * 1024 + kt * 64 + srow) * 64 + schunk * 8;
            __builtin_amdgcn_global_load_lds((const AS1 void*)gk,        (AS3 void*)&Ks[t * 8],         16, 0, 0);
            __builtin_amdgcn_global_load_lds((const AS1 void*)(gk + 32), (AS3 void*)&Ks[(t + 256) * 8], 16, 0, 0);
            const short* gv = Vt + ((size_t)bh * 64 + srow) * 1024 + kt * 64 + schunk * 8;
            __builtin_amdgcn_global_load_lds((const AS1 void*)gv,       (AS3 void*)&Vs[t * 8],         16, 0, 0);
            __builtin_amdgcn_global_load_lds((const AS1 void*)(gv + 32),(AS3 void*)&Vs[(t + 256) * 8], 16, 0, 0);
        }
        __syncthreads();

        // S = Q K^T : wave computes 16 queries x 64 keys (4 n-frags x 2 k-halves)
        bf16x8 qa[2];
#pragma unroll
        for (int kh = 0; kh < 2; ++kh)
            qa[kh] = *(const bf16x8*)&Qs[((quad + 4 * kh) * 64 + w * 16 + l16) * 8];

        f32x4 S[4];
#pragma unroll
        for (int n = 0; n < 4; ++n) S[n] = (f32x4){0.f, 0.f, 0.f, 0.f};
#pragma unroll
        for (int kh = 0; kh < 2; ++kh)
#pragma unroll
            for (int n = 0; n < 4; ++n) {
                const bf16x8 kb = *(const bf16x8*)&Ks[((quad + 4 * kh) * 64 + n * 16 + l16) * 8];
                S[n] = __builtin_amdgcn_mfma_f32_16x16x32_bf16(qa[kh], kb, S[n], 0, 0, 0);
            }

        // Online softmax per query row (row = quad*4 + r; 16 col lanes share it)
#pragma unroll
        for (int r = 0; r < 4; ++r) {
            float mx = fmaxf(fmaxf(S[0][r], S[1][r]), fmaxf(S[2][r], S[3][r]));
            mx = fmaxf(mx, __shfl_xor(mx, 1));
            mx = fmaxf(mx, __shfl_xor(mx, 2));
            mx = fmaxf(mx, __shfl_xor(mx, 4));
            mx = fmaxf(mx, __shfl_xor(mx, 8));
            const float mnew  = fmaxf(m_i[r], mx);
            const float alpha = __expf(m_i[r] - mnew);
            m_i[r] = mnew;
            float rs = 0.f;
            float p[4];
#pragma unroll
            for (int n = 0; n < 4; ++n) { p[n] = __expf(S[n][r] - mnew); rs += p[n]; }
            rs += __shfl_xor(rs, 1);
            rs += __shfl_xor(rs, 2);
            rs += __shfl_xor(rs, 4);
            rs += __shfl_xor(rs, 8);
            l_i[r] = l_i[r] * alpha + rs;
#pragma unroll
            for (int nd = 0; nd < 4; ++nd) O[nd][r] *= alpha;
            // write P (bf16) into wave-private A-layout: [kchunk][qrow16][8]
#pragma unroll
            for (int n = 0; n < 4; ++n) {
                const int key = n * 16 + l16;
                Psw[((key >> 3) * 16 + quad * 4 + r) * 8 + (key & 7)] =
                    (short)(unsigned short)bf16_rne(p[n]);
            }
        }

        // O += P V : A from Psw (m=query=l16), B from Vs (n=dim=l16)
        bf16x8 pa[2];
#pragma unroll
        for (int kh = 0; kh < 2; ++kh)
            pa[kh] = *(const bf16x8*)&Psw[((quad + 4 * kh) * 16 + l16) * 8];
#pragma unroll
        for (int kh = 0; kh < 2; ++kh)
#pragma unroll
            for (int nd = 0; nd < 4; ++nd) {
                const bf16x8 vb = *(const bf16x8*)&Vs[((quad + 4 * kh) * 64 + nd * 16 + l16) * 8];
                O[nd] = __builtin_amdgcn_mfma_f32_16x16x32_bf16(pa[kh], vb, O[nd], 0, 0, 0);
            }
    }

    // Epilogue: normalize, store fp32 [b,h,l,d] flat
#pragma unroll
    for (int r = 0; r < 4; ++r) {
        const float inv = 1.0f / l_i[r];
        const int query = qt * 64 + w * 16 + quad * 4 + r;
        float* p = out + ((size_t)bh * 1024 + query) * 64;
#pragma unroll
        for (int nd = 0; nd < 4; ++nd) p[nd * 16 + l16] = O[nd][r] * inv;
    }
}

extern "C" void kernel_launch(void* const* d_in, const int* in_sizes, int n_in,
                              void* d_out, int out_size, void* d_ws, size_t ws_size,
                              hipStream_t stream)
{
    const float* X  = (const float*)d_in[0];
    const float* Wq = (const float*)d_in[1];
    const float* bq = (const float*)d_in[2];
    const float* Wk = (const float*)d_in[3];
    const float* bk = (const float*)d_in[4];
    const float* Wv = (const float*)d_in[5];
    const float* bv = (const float*)d_in[6];
    float* out = (float*)d_out;

    const size_t per = (size_t)8 * HEADS * 1024 * HDIM;   // 8,388,608
    short* Qb = (short*)d_ws;
    short* Kb = Qb + per;
    short* Vt = Kb + per;
    short* Xh = Vt + per;
    short* Xl = Xh + per;
    short* Wh = Xl + per;                 // 3 x 1,048,576
    short* Wl = Wh + 3 * 1048576;

    const int nX = (int)per;
    const int nW = 1048576;

    split_bf16<<<nX / (8 * 256), 256, 0, stream>>>(X,  Xh, Xl, nX);
    split_bf16<<<nW / (8 * 256), 256, 0, stream>>>(Wq, Wh,          Wl,          nW);
    split_bf16<<<nW / (8 * 256), 256, 0, stream>>>(Wk, Wh + nW,     Wl + nW,     nW);
    split_bf16<<<nW / (8 * 256), 256, 0, stream>>>(Wv, Wh + 2 * nW, Wl + 2 * nW, nW);

    qkv_mfma<<<dim3(24, 64), 256, 0, stream>>>(Xh, Xl, Wh, Wl, bq, bk, bv, Qb, Kb, Vt);
    attn_mfma<<<dim3(16, HEADS, 8), 256, 0, stream>>>(Qb, Kb, Vt, out);
}